// Round 7
// baseline (259.649 us; speedup 1.0000x reference)
//
#include <hip/hip_runtime.h>

// ContinuousNormalizingFlow: B=32768 rows, D=8, H=64, 100 Euler steps.
// R23: h-split wave pairing. Evidence through R22: wall responds ONLY to
// per-wave op count at ~6.5cy/op (R20/R21 cuts linear, R22 ILP move null),
// 2 waves/SIMD is register-capped (188 unified regs), duplicating work to
// get waves loses 1:1 (R18). => per-op wall cost ~ latency/TLP; the only
// remaining lever is op-CONSERVING TLP increase. Split the hidden dim:
// wave pairs (w, w^1) share 16 rows; each wave owns H-half = mt {0,1} or
// {2,3}. Per wave: trans 64->32, MFMA 30->15, frags halved -> fits the
// 128-reg budget of launch_bounds(256,4) -> 4096 waves, 4/SIMD from 4
// different WGs (uncorrelated stalls). Cost: 2 LDS exchanges + 2 barriers
// per iter (sigma/s halves after L1; d3 partials, summed commutatively so
// both waves keep bit-identical xr). a2d is B-side folded (cpkC) to buy
// register fit; a2g stays pre-folded (absorbs w3c). Math = R21 exactly.

#define TSCALE 2.885390081777926815f // 2*log2(e)

// s = 1/(2^z + 1)  (z pre-scaled by 2*log2e). th = 1-2s. inf-safe.
__device__ __forceinline__ float frcp3(float z) {
    float e = __builtin_amdgcn_exp2f(z);
    return __builtin_amdgcn_rcpf(e + 1.0f);
}

typedef __attribute__((ext_vector_type(8))) _Float16 v8h; // 8 f16 (4 VGPRs)
typedef __attribute__((ext_vector_type(2))) __fp16 v2fp; // cvt_pkrtz result
typedef __attribute__((ext_vector_type(4))) float v4f;   // MFMA C/D
typedef __attribute__((ext_vector_type(2))) float v2f;   // packed fp32 pair

union FragU {
    v8h h;
    unsigned u[4];
};

__device__ __forceinline__ unsigned pk16(float a, float b) {
    v2fp t = __builtin_amdgcn_cvt_pkrtz(a, b);
    return __builtin_bit_cast(unsigned, t);
}
__device__ __forceinline__ unsigned pk16v(v2f v) { return pk16(v.x, v.y); }

// sigma = s - s^2 = om/4 on a packed f16 pair.
__device__ __forceinline__ unsigned pksig(unsigned sp) {
    v2fp s = __builtin_bit_cast(v2fp, sp);
    v2fp r = s - s * s;
    return __builtin_bit_cast(unsigned, r);
}
// packed f16 multiply (one v_pk_mul_f16).
__device__ __forceinline__ unsigned pmul16(unsigned a, unsigned b) {
    v2fp x = __builtin_bit_cast(v2fp, a);
    v2fp y = __builtin_bit_cast(v2fp, b);
    v2fp r = x * y;
    return __builtin_bit_cast(unsigned, r);
}

// K-permutation for full-K W2 frags: slot (ks,q,jj) <- physical j.
__device__ __forceinline__ int physj(int ks, int q, int jj) {
    return 16 * (ks + 2 * (jj >> 2)) + 4 * q + (jj & 3);
}

// Assemble the 4 C-layout mt-packs from own half (o0,o1) + sibling uint4.
__device__ __forceinline__ void asm4(int half, uint2 o0, uint2 o1, uint4 s,
                                     uint2& p0, uint2& p1, uint2& p2, uint2& p3) {
    if (half == 0) {
        p0 = o0; p1 = o1;
        p2 = uint2{s.x, s.y}; p3 = uint2{s.z, s.w};
    } else {
        p0 = uint2{s.x, s.y}; p1 = uint2{s.z, s.w};
        p2 = o0; p3 = o1;
    }
}

__global__ __launch_bounds__(256, 4) void cnf_fused(
    const float* __restrict__ x0, const float* __restrict__ W1,
    const float* __restrict__ b1, const float* __restrict__ W2,
    const float* __restrict__ b2, const float* __restrict__ W3,
    const float* __restrict__ b3, const int* __restrict__ nsp,
    float* __restrict__ out, int rows) {
    const int tid = threadIdx.x;
    const int w = tid >> 6;
    const int lane = tid & 63;
    const int c = lane & 15;
    const int q = lane >> 4;
    const int pair = w >> 1;
    const int half = w & 1;
    const int mtb = 2 * half; // own mt tiles: mtb, mtb+1 (h-half)
    const int ws = w ^ 1;     // sibling wave in the pair
    const int row0 = blockIdx.x * 32 + pair * 16;

    __shared__ unsigned ex1[4][64][8]; // s-packs [0..3], sigma-packs [4..7]
    __shared__ float ex2[4][64][8];    // d3 partials in [0..3] (padded row)

    const int n = *nsp;
    const float dt = 1.0f / (float)n;

    // ---- A1 (x TSCALE), own-half rows ----
    FragU a1h[2];
#pragma unroll
    for (int jmt = 0; jmt < 2; ++jmt) {
        const int m = 16 * (mtb + jmt) + c;
        float f[8] = {0.f, 0.f, 0.f, 0.f, 0.f, 0.f, 0.f, 0.f};
        if (q == 0) {
#pragma unroll
            for (int jj = 0; jj < 4; ++jj) f[jj] = TSCALE * W1[m * 9 + jj];
            f[4] = TSCALE * W1[m * 9 + 8];
            f[5] = TSCALE * b1[m];
        } else if (q == 1) {
#pragma unroll
            for (int jj = 0; jj < 4; ++jj) f[jj] = TSCALE * W1[m * 9 + 4 + jj];
        }
#pragma unroll
        for (int p = 0; p < 4; ++p) a1h[jmt].u[p] = pk16(f[2 * p], f[2 * p + 1]);
    }
    // ---- A2 (x -2*TSCALE) and A2g (16*w3c*W2*w1r), own-half rows, full K ----
    FragU a2h[2][2], a2gh[2][2];
#pragma unroll
    for (int jmt = 0; jmt < 2; ++jmt) {
        const int m = 16 * (mtb + jmt) + c;
        float w3cm = 0.f;
#pragma unroll
        for (int d = 0; d < 8; ++d) w3cm += W3[d * 64 + m];
#pragma unroll
        for (int ks = 0; ks < 2; ++ks) {
            float f[8], fg[8];
#pragma unroll
            for (int jj = 0; jj < 8; ++jj) {
                const int pj = physj(ks, q, jj);
                const float wv = W2[m * 64 + pj];
                float w1r = 0.f;
#pragma unroll
                for (int k = 0; k < 8; ++k) w1r += W1[pj * 9 + k];
                f[jj] = -2.0f * TSCALE * wv;
                fg[jj] = 16.0f * w3cm * wv * w1r;
            }
#pragma unroll
            for (int p = 0; p < 4; ++p) {
                a2h[jmt][ks].u[p] = pk16(f[2 * p], f[2 * p + 1]);
                a2gh[jmt][ks].u[p] = pk16(fg[2 * p], fg[2 * p + 1]);
            }
        }
    }
    // ---- cpkC: B-side fold constants for dz2 (C-layout, ALL mt; full K).
    // dz2 = a2 x (sigma (x) c), c(j) = -4*dt*w1t(j)/TSCALE. ----
    uint2 cpkC[4];
    {
        const float cs = -4.0f * dt / TSCALE;
#pragma unroll
        for (int mt = 0; mt < 4; ++mt) {
            const int j0 = 16 * mt + 4 * q;
            cpkC[mt].x = pk16(cs * W1[j0 * 9 + 8], cs * W1[(j0 + 1) * 9 + 8]);
            cpkC[mt].y = pk16(cs * W1[(j0 + 2) * 9 + 8], cs * W1[(j0 + 3) * 9 + 8]);
        }
    }
    // ---- A3 half (x -2): K=32 frag over own h-half; slot (q,jj) <-
    // h = 16*(mtb + (jj>>2)) + 4q + (jj&3)  (matches bu_own build) ----
    FragU a3h;
    {
        float f[8];
#pragma unroll
        for (int jj = 0; jj < 8; ++jj)
            f[jj] = -2.0f * W3[(c & 7) * 64 + 16 * (mtb + (jj >> 2)) + 4 * q + (jj & 3)];
#pragma unroll
        for (int p = 0; p < 4; ++p) a3h.u[p] = pk16(f[2 * p], f[2 * p + 1]);
    }

    const v4f vzero = {0.f, 0.f, 0.f, 0.f};
    FragU ones;
    ones.u[0] = ones.u[1] = ones.u[2] = ones.u[3] = 0x3C003C00u;

    // ---- vb2h = TSCALE*(b2 + rowsum(W2)) for own rows ----
    v4f vb2h[2];
#pragma unroll
    for (int jmt = 0; jmt < 2; ++jmt) {
        v4f t = __builtin_amdgcn_mfma_f32_16x16x32_f16(a2h[jmt][0].h, ones.h, vzero, 0, 0, 0);
        t = __builtin_amdgcn_mfma_f32_16x16x32_f16(a2h[jmt][1].h, ones.h, t, 0, 0, 0);
        const int j0 = 16 * (mtb + jmt) + 4 * q;
#pragma unroll
        for (int r = 0; r < 4; ++r) vb2h[jmt][r] = TSCALE * b2[j0 + r] - 0.5f * t[r];
    }
    // ---- vb3 partial: own half-rowsum of W3; b3 carried by half==0 only.
    // d3 = d3p_A + d3p_B then includes full b3 + rowsum(W3). ----
    v4f vb3p;
    {
        v4f t = __builtin_amdgcn_mfma_f32_16x16x32_f16(a3h.h, ones.h, vzero, 0, 0, 0);
#pragma unroll
        for (int r = 0; r < 4; ++r)
            vb3p[r] = (half == 0 ? b3[(4 * q + r) & 7] : 0.0f) - 0.5f * t[r];
    }

    // ---- x state (duplicated across the pair; updates bit-identical) ----
    float xr[4];
    {
        float4 v = *(const float4*)(x0 + (size_t)(row0 + c) * 8 + 4 * (q & 1));
        xr[0] = v.x; xr[1] = v.y; xr[2] = v.z; xr[3] = v.w;
    }
    v2f gv = {0.f, 0.f};

    // ================= iteration 0: pure forward at (x0, t=0) =================
    {
        FragU bx;
        bx.u[0] = pk16(xr[0], xr[1]);
        bx.u[1] = pk16(xr[2], xr[3]);
        bx.u[2] = pk16(0.0f, 1.0f);
        bx.u[3] = 0u;
        v4f d1h[2];
#pragma unroll
        for (int jmt = 0; jmt < 2; ++jmt)
            d1h[jmt] = __builtin_amdgcn_mfma_f32_16x16x32_f16(a1h[jmt].h, bx.h, vzero, 0, 0, 0);
        uint2 ob0, ob1;
        ob0.x = pk16(frcp3(d1h[0][0]), frcp3(d1h[0][1]));
        ob0.y = pk16(frcp3(d1h[0][2]), frcp3(d1h[0][3]));
        ob1.x = pk16(frcp3(d1h[1][0]), frcp3(d1h[1][1]));
        ob1.y = pk16(frcp3(d1h[1][2]), frcp3(d1h[1][3]));
        *(uint4*)&ex1[w][lane][0] = uint4{ob0.x, ob0.y, ob1.x, ob1.y};
        __syncthreads();
        const uint4 ssb = *(const uint4*)&ex1[ws][lane][0];
        uint2 p0, p1, p2, p3;
        asm4(half, ob0, ob1, ssb, p0, p1, p2, p3);
        FragU bs[2];
        bs[0].u[0] = p0.x; bs[0].u[1] = p0.y; bs[0].u[2] = p2.x; bs[0].u[3] = p2.y;
        bs[1].u[0] = p1.x; bs[1].u[1] = p1.y; bs[1].u[2] = p3.x; bs[1].u[3] = p3.y;
        v4f z2h[2];
#pragma unroll
        for (int jmt = 0; jmt < 2; ++jmt) {
            z2h[jmt] = __builtin_amdgcn_mfma_f32_16x16x32_f16(a2h[jmt][0].h, bs[0].h, vb2h[jmt], 0, 0, 0);
            z2h[jmt] = __builtin_amdgcn_mfma_f32_16x16x32_f16(a2h[jmt][1].h, bs[1].h, z2h[jmt], 0, 0, 0);
        }
        FragU buo;
        buo.u[0] = pk16(frcp3(z2h[0][0]), frcp3(z2h[0][1]));
        buo.u[1] = pk16(frcp3(z2h[0][2]), frcp3(z2h[0][3]));
        buo.u[2] = pk16(frcp3(z2h[1][0]), frcp3(z2h[1][1]));
        buo.u[3] = pk16(frcp3(z2h[1][2]), frcp3(z2h[1][3]));
        v4f d3p = __builtin_amdgcn_mfma_f32_16x16x32_f16(a3h.h, buo.h, vb3p, 0, 0, 0);
        *(float4*)&ex2[w][lane][0] = float4{d3p[0], d3p[1], d3p[2], d3p[3]};
        __syncthreads();
        const float4 dss = *(const float4*)&ex2[ws][lane][0];
        xr[0] = fmaf(dt, d3p[0] + dss.x, xr[0]);
        xr[1] = fmaf(dt, d3p[1] + dss.y, xr[1]);
        xr[2] = fmaf(dt, d3p[2] + dss.z, xr[2]);
        xr[3] = fmaf(dt, d3p[3] + dss.w, xr[3]);
    }

    // ====== iterations i = 1..n-1: bwd(i-1) + fwd(i) from one L1 eval ======
    float tp = 0.0f; // t_{i-1}
    for (int i = 1; i < n; ++i) {
        FragU bx; // [x_i; t_{i-1}; 1]
        bx.u[0] = pk16(xr[0], xr[1]);
        bx.u[1] = pk16(xr[2], xr[3]);
        bx.u[2] = pk16(tp, 1.0f);
        bx.u[3] = 0u;
        tp += dt;
        v4f d1h[2];
#pragma unroll
        for (int jmt = 0; jmt < 2; ++jmt)
            d1h[jmt] = __builtin_amdgcn_mfma_f32_16x16x32_f16(a1h[jmt].h, bx.h, vzero, 0, 0, 0);

        // layer-1 own half: s1 (3-op chains), sigma1 packed f16
        uint2 ob0, ob1, og0, og1;
        ob0.x = pk16(frcp3(d1h[0][0]), frcp3(d1h[0][1]));
        ob0.y = pk16(frcp3(d1h[0][2]), frcp3(d1h[0][3]));
        ob1.x = pk16(frcp3(d1h[1][0]), frcp3(d1h[1][1]));
        ob1.y = pk16(frcp3(d1h[1][2]), frcp3(d1h[1][3]));
        og0.x = pksig(ob0.x); og0.y = pksig(ob0.y);
        og1.x = pksig(ob1.x); og1.y = pksig(ob1.y);

        // exchange 1: s-half + sigma-half
        *(uint4*)&ex1[w][lane][0] = uint4{ob0.x, ob0.y, ob1.x, ob1.y};
        *(uint4*)&ex1[w][lane][4] = uint4{og0.x, og0.y, og1.x, og1.y};
        __syncthreads();
        const uint4 ssb = *(const uint4*)&ex1[ws][lane][0];
        const uint4 ssg = *(const uint4*)&ex1[ws][lane][4];
        uint2 pb0, pb1, pb2, pb3, pg0, pg1, pg2, pg3;
        asm4(half, ob0, ob1, ssb, pb0, pb1, pb2, pb3);
        asm4(half, og0, og1, ssg, pg0, pg1, pg2, pg3);
        FragU bs[2], bo[2], bo2[2];
        bs[0].u[0] = pb0.x; bs[0].u[1] = pb0.y; bs[0].u[2] = pb2.x; bs[0].u[3] = pb2.y;
        bs[1].u[0] = pb1.x; bs[1].u[1] = pb1.y; bs[1].u[2] = pb3.x; bs[1].u[3] = pb3.y;
        bo[0].u[0] = pg0.x; bo[0].u[1] = pg0.y; bo[0].u[2] = pg2.x; bo[0].u[3] = pg2.y;
        bo[1].u[0] = pg1.x; bo[1].u[1] = pg1.y; bo[1].u[2] = pg3.x; bo[1].u[3] = pg3.y;
        // dz2's B: sigma (x) c (pre-rename fold with C-layout constants)
        bo2[0].u[0] = pmul16(pg0.x, cpkC[0].x); bo2[0].u[1] = pmul16(pg0.y, cpkC[0].y);
        bo2[0].u[2] = pmul16(pg2.x, cpkC[2].x); bo2[0].u[3] = pmul16(pg2.y, cpkC[2].y);
        bo2[1].u[0] = pmul16(pg1.x, cpkC[1].x); bo2[1].u[1] = pmul16(pg1.y, cpkC[1].y);
        bo2[1].u[2] = pmul16(pg3.x, cpkC[3].x); bo2[1].u[3] = pmul16(pg3.y, cpkC[3].y);

        v4f z2bh[2], sgh[2], dz2h[2];
#pragma unroll
        for (int jmt = 0; jmt < 2; ++jmt) {
            z2bh[jmt] = __builtin_amdgcn_mfma_f32_16x16x32_f16(a2h[jmt][0].h, bs[0].h, vb2h[jmt], 0, 0, 0);
            z2bh[jmt] = __builtin_amdgcn_mfma_f32_16x16x32_f16(a2h[jmt][1].h, bs[1].h, z2bh[jmt], 0, 0, 0);
            sgh[jmt] = __builtin_amdgcn_mfma_f32_16x16x32_f16(a2gh[jmt][0].h, bo[0].h, vzero, 0, 0, 0);
            sgh[jmt] = __builtin_amdgcn_mfma_f32_16x16x32_f16(a2gh[jmt][1].h, bo[1].h, sgh[jmt], 0, 0, 0);
            dz2h[jmt] = __builtin_amdgcn_mfma_f32_16x16x32_f16(a2h[jmt][0].h, bo2[0].h, vzero, 0, 0, 0);
            dz2h[jmt] = __builtin_amdgcn_mfma_f32_16x16x32_f16(a2h[jmt][1].h, bo2[1].h, dz2h[jmt], 0, 0, 0);
        }

        // layer-2 own half: s2, sigma2; gv += sigma2*sg; u = s2 - sigma2*dz2
        uint2 pu[2];
#pragma unroll
        for (int jmt = 0; jmt < 2; ++jmt) {
            v2f s01 = {frcp3(z2bh[jmt][0]), frcp3(z2bh[jmt][1])};
            v2f s23 = {frcp3(z2bh[jmt][2]), frcp3(z2bh[jmt][3])};
            v2f g01 = s01 - s01 * s01;
            v2f g23 = s23 - s23 * s23;
            gv += g01 * v2f{sgh[jmt][0], sgh[jmt][1]};
            gv += g23 * v2f{sgh[jmt][2], sgh[jmt][3]};
            v2f u01 = s01 - g01 * v2f{dz2h[jmt][0], dz2h[jmt][1]};
            v2f u23 = s23 - g23 * v2f{dz2h[jmt][2], dz2h[jmt][3]};
            pu[jmt].x = pk16v(u01);
            pu[jmt].y = pk16v(u23);
        }
        // d3 partial over own h-half, then exchange partials (commutative add)
        FragU buo;
        buo.u[0] = pu[0].x; buo.u[1] = pu[0].y; buo.u[2] = pu[1].x; buo.u[3] = pu[1].y;
        v4f d3p = __builtin_amdgcn_mfma_f32_16x16x32_f16(a3h.h, buo.h, vb3p, 0, 0, 0);
        *(float4*)&ex2[w][lane][0] = float4{d3p[0], d3p[1], d3p[2], d3p[3]};
        __syncthreads();
        const float4 dss = *(const float4*)&ex2[ws][lane][0];
        xr[0] = fmaf(dt, d3p[0] + dss.x, xr[0]);
        xr[1] = fmaf(dt, d3p[1] + dss.y, xr[1]);
        xr[2] = fmaf(dt, d3p[2] + dss.z, xr[2]);
        xr[3] = fmaf(dt, d3p[3] + dss.w, xr[3]);
    }

    // ============ final bwd at (x_n, t_{n-1}) ============
    {
        FragU bx;
        bx.u[0] = pk16(xr[0], xr[1]);
        bx.u[1] = pk16(xr[2], xr[3]);
        bx.u[2] = pk16(tp, 1.0f); // tp == (n-1)*dt
        bx.u[3] = 0u;
        v4f d1h[2];
#pragma unroll
        for (int jmt = 0; jmt < 2; ++jmt)
            d1h[jmt] = __builtin_amdgcn_mfma_f32_16x16x32_f16(a1h[jmt].h, bx.h, vzero, 0, 0, 0);
        uint2 ob0, ob1, og0, og1;
        ob0.x = pk16(frcp3(d1h[0][0]), frcp3(d1h[0][1]));
        ob0.y = pk16(frcp3(d1h[0][2]), frcp3(d1h[0][3]));
        ob1.x = pk16(frcp3(d1h[1][0]), frcp3(d1h[1][1]));
        ob1.y = pk16(frcp3(d1h[1][2]), frcp3(d1h[1][3]));
        og0.x = pksig(ob0.x); og0.y = pksig(ob0.y);
        og1.x = pksig(ob1.x); og1.y = pksig(ob1.y);
        *(uint4*)&ex1[w][lane][0] = uint4{ob0.x, ob0.y, ob1.x, ob1.y};
        *(uint4*)&ex1[w][lane][4] = uint4{og0.x, og0.y, og1.x, og1.y};
        __syncthreads();
        const uint4 ssb = *(const uint4*)&ex1[ws][lane][0];
        const uint4 ssg = *(const uint4*)&ex1[ws][lane][4];
        uint2 pb0, pb1, pb2, pb3, pg0, pg1, pg2, pg3;
        asm4(half, ob0, ob1, ssb, pb0, pb1, pb2, pb3);
        asm4(half, og0, og1, ssg, pg0, pg1, pg2, pg3);
        FragU bs[2], bo[2];
        bs[0].u[0] = pb0.x; bs[0].u[1] = pb0.y; bs[0].u[2] = pb2.x; bs[0].u[3] = pb2.y;
        bs[1].u[0] = pb1.x; bs[1].u[1] = pb1.y; bs[1].u[2] = pb3.x; bs[1].u[3] = pb3.y;
        bo[0].u[0] = pg0.x; bo[0].u[1] = pg0.y; bo[0].u[2] = pg2.x; bo[0].u[3] = pg2.y;
        bo[1].u[0] = pg1.x; bo[1].u[1] = pg1.y; bo[1].u[2] = pg3.x; bo[1].u[3] = pg3.y;
        v4f z2bh[2], sgh[2];
#pragma unroll
        for (int jmt = 0; jmt < 2; ++jmt) {
            z2bh[jmt] = __builtin_amdgcn_mfma_f32_16x16x32_f16(a2h[jmt][0].h, bs[0].h, vb2h[jmt], 0, 0, 0);
            z2bh[jmt] = __builtin_amdgcn_mfma_f32_16x16x32_f16(a2h[jmt][1].h, bs[1].h, z2bh[jmt], 0, 0, 0);
            sgh[jmt] = __builtin_amdgcn_mfma_f32_16x16x32_f16(a2gh[jmt][0].h, bo[0].h, vzero, 0, 0, 0);
            sgh[jmt] = __builtin_amdgcn_mfma_f32_16x16x32_f16(a2gh[jmt][1].h, bo[1].h, sgh[jmt], 0, 0, 0);
        }
#pragma unroll
        for (int jmt = 0; jmt < 2; ++jmt) {
            v2f s01 = {frcp3(z2bh[jmt][0]), frcp3(z2bh[jmt][1])};
            v2f s23 = {frcp3(z2bh[jmt][2]), frcp3(z2bh[jmt][3])};
            v2f g01 = s01 - s01 * s01;
            v2f g23 = s23 - s23 * s23;
            gv += g01 * v2f{sgh[jmt][0], sgh[jmt][1]};
            gv += g23 * v2f{sgh[jmt][2], sgh[jmt][3]};
        }
    }

    // ---- epilogue: per-wave q-reduce, then pair-sum via LDS ----
    float g = gv.x + gv.y;
    g += __shfl_xor(g, 16);
    g += __shfl_xor(g, 32);
    ex2[w][lane][0] = g;
    __syncthreads();
    g += ex2[ws][lane][0];
    if (half == 0 && q < 2) {
        float4 st = {xr[0], xr[1], xr[2], xr[3]};
        *(float4*)(out + (size_t)(row0 + c) * 8 + 4 * q) = st;
    }
    if (half == 0 && q == 0) out[(size_t)rows * 8 + row0 + c] = dt * g;
}

extern "C" void kernel_launch(void* const* d_in, const int* in_sizes, int n_in,
                              void* d_out, int out_size, void* d_ws, size_t ws_size,
                              hipStream_t stream) {
    const float* x0 = (const float*)d_in[0];
    const float* W1 = (const float*)d_in[1];
    const float* b1 = (const float*)d_in[2];
    const float* W2 = (const float*)d_in[3];
    const float* b2 = (const float*)d_in[4];
    const float* W3 = (const float*)d_in[5];
    const float* b3 = (const float*)d_in[6];
    const int* ns = (const int*)d_in[7];
    float* out = (float*)d_out;
    const int rows = in_sizes[0] / 8; // 32768

    // 16 rows per wave-PAIR, 2 pairs per 256-thread block -> rows/32 blocks.
    hipLaunchKernelGGL(cnf_fused, dim3(rows / 32), dim3(256), 0, stream,
                       x0, W1, b1, W2, b2, W3, b3, ns, out, rows);
}

// Round 8
// 244.268 us; speedup vs baseline: 1.0630x; 1.0630x over previous
//
#include <hip/hip_runtime.h>

// ContinuousNormalizingFlow: B=32768 rows, D=8, H=64, 100 Euler steps.
// R24: h-split wave pairing, attempt 2. R23 post-mortem: concept worked
// (occupancy 36%, bit-identical output) but died on (a) spills --
// (256,4)'s 128-unified budget vs ~150 live regs -> 200MB scratch traffic
// per dispatch, memory-bound at 950GB/s; (b) 16-way LDS bank conflicts
// from the 32B lane stride (1.49e7 counted). Fixes:
//   1. launch_bounds(256,3): 170-reg budget fits the state (accept a
//      ~1/4 tail round: 1024 blocks at 3 resident/CU).
//   2. No sigma exchange: sigma = pksig(s) is deterministic from the f16
//      s bits, so each wave recomputes it from the assembled full-K
//      s-packs (8 pksig, -8 live regs, half the ex1 traffic).
//   3. LDS inner stride = 5 words (20B): gcd(5,32)=1 -> banks uniform,
//      2-way max aliasing (free); word-wise b32 access.
// Math identical to R21/R22/R23 (s-form tanh, folded scales); xr stays
// bit-identical across the pair (commutative f32 partial-sum).

#define TSCALE 2.885390081777926815f // 2*log2(e)

// s = 1/(2^z + 1)  (z pre-scaled by 2*log2e). th = 1-2s. inf-safe.
__device__ __forceinline__ float frcp3(float z) {
    float e = __builtin_amdgcn_exp2f(z);
    return __builtin_amdgcn_rcpf(e + 1.0f);
}

typedef __attribute__((ext_vector_type(8))) _Float16 v8h; // 8 f16 (4 VGPRs)
typedef __attribute__((ext_vector_type(2))) __fp16 v2fp; // cvt_pkrtz result
typedef __attribute__((ext_vector_type(4))) float v4f;   // MFMA C/D
typedef __attribute__((ext_vector_type(2))) float v2f;   // packed fp32 pair

union FragU {
    v8h h;
    unsigned u[4];
};

__device__ __forceinline__ unsigned pk16(float a, float b) {
    v2fp t = __builtin_amdgcn_cvt_pkrtz(a, b);
    return __builtin_bit_cast(unsigned, t);
}
__device__ __forceinline__ unsigned pk16v(v2f v) { return pk16(v.x, v.y); }

// sigma = s - s^2 = om/4 on a packed f16 pair.
__device__ __forceinline__ unsigned pksig(unsigned sp) {
    v2fp s = __builtin_bit_cast(v2fp, sp);
    v2fp r = s - s * s;
    return __builtin_bit_cast(unsigned, r);
}
// packed f16 multiply (one v_pk_mul_f16).
__device__ __forceinline__ unsigned pmul16(unsigned a, unsigned b) {
    v2fp x = __builtin_bit_cast(v2fp, a);
    v2fp y = __builtin_bit_cast(v2fp, b);
    v2fp r = x * y;
    return __builtin_bit_cast(unsigned, r);
}

// K-permutation for full-K W2 frags: slot (ks,q,jj) <- physical j.
__device__ __forceinline__ int physj(int ks, int q, int jj) {
    return 16 * (ks + 2 * (jj >> 2)) + 4 * q + (jj & 3);
}

__global__ __launch_bounds__(256, 3) void cnf_fused(
    const float* __restrict__ x0, const float* __restrict__ W1,
    const float* __restrict__ b1, const float* __restrict__ W2,
    const float* __restrict__ b2, const float* __restrict__ W3,
    const float* __restrict__ b3, const int* __restrict__ nsp,
    float* __restrict__ out, int rows) {
    const int tid = threadIdx.x;
    const int w = tid >> 6;
    const int lane = tid & 63;
    const int c = lane & 15;
    const int q = lane >> 4;
    const int pair = w >> 1;
    const int half = w & 1;
    const int mtb = 2 * half; // own mt tiles: mtb, mtb+1 (h-half)
    const int ws = w ^ 1;     // sibling wave in the pair
    const int row0 = blockIdx.x * 32 + pair * 16;

    // stride-5 words: bank = (5*idx)%32, gcd(5,32)=1 -> 2-way max (free).
    __shared__ unsigned ex1[4][64][5]; // s-packs, 4 words used
    __shared__ float ex2[4][64][5];    // d3 partials / g, 4 words used

    const int n = *nsp;
    const float dt = 1.0f / (float)n;

    // ---- A1 (x TSCALE), own-half rows ----
    FragU a1h[2];
#pragma unroll
    for (int jmt = 0; jmt < 2; ++jmt) {
        const int m = 16 * (mtb + jmt) + c;
        float f[8] = {0.f, 0.f, 0.f, 0.f, 0.f, 0.f, 0.f, 0.f};
        if (q == 0) {
#pragma unroll
            for (int jj = 0; jj < 4; ++jj) f[jj] = TSCALE * W1[m * 9 + jj];
            f[4] = TSCALE * W1[m * 9 + 8];
            f[5] = TSCALE * b1[m];
        } else if (q == 1) {
#pragma unroll
            for (int jj = 0; jj < 4; ++jj) f[jj] = TSCALE * W1[m * 9 + 4 + jj];
        }
#pragma unroll
        for (int p = 0; p < 4; ++p) a1h[jmt].u[p] = pk16(f[2 * p], f[2 * p + 1]);
    }
    // ---- A2 (x -2*TSCALE) and A2g (16*w3c*W2*w1r), own-half rows, full K ----
    FragU a2h[2][2], a2gh[2][2];
#pragma unroll
    for (int jmt = 0; jmt < 2; ++jmt) {
        const int m = 16 * (mtb + jmt) + c;
        float w3cm = 0.f;
#pragma unroll
        for (int d = 0; d < 8; ++d) w3cm += W3[d * 64 + m];
#pragma unroll
        for (int ks = 0; ks < 2; ++ks) {
            float f[8], fg[8];
#pragma unroll
            for (int jj = 0; jj < 8; ++jj) {
                const int pj = physj(ks, q, jj);
                const float wv = W2[m * 64 + pj];
                float w1r = 0.f;
#pragma unroll
                for (int k = 0; k < 8; ++k) w1r += W1[pj * 9 + k];
                f[jj] = -2.0f * TSCALE * wv;
                fg[jj] = 16.0f * w3cm * wv * w1r;
            }
#pragma unroll
            for (int p = 0; p < 4; ++p) {
                a2h[jmt][ks].u[p] = pk16(f[2 * p], f[2 * p + 1]);
                a2gh[jmt][ks].u[p] = pk16(fg[2 * p], fg[2 * p + 1]);
            }
        }
    }
    // ---- cpkC: B-side fold constants for dz2 (C-layout, ALL mt; full K).
    // dz2 = a2 x (sigma (x) c), c(j) = -4*dt*w1t(j)/TSCALE. ----
    uint2 cpkC[4];
    {
        const float cs = -4.0f * dt / TSCALE;
#pragma unroll
        for (int mt = 0; mt < 4; ++mt) {
            const int j0 = 16 * mt + 4 * q;
            cpkC[mt].x = pk16(cs * W1[j0 * 9 + 8], cs * W1[(j0 + 1) * 9 + 8]);
            cpkC[mt].y = pk16(cs * W1[(j0 + 2) * 9 + 8], cs * W1[(j0 + 3) * 9 + 8]);
        }
    }
    // ---- A3 half (x -2): K=32 frag over own h-half ----
    FragU a3h;
    {
        float f[8];
#pragma unroll
        for (int jj = 0; jj < 8; ++jj)
            f[jj] = -2.0f * W3[(c & 7) * 64 + 16 * (mtb + (jj >> 2)) + 4 * q + (jj & 3)];
#pragma unroll
        for (int p = 0; p < 4; ++p) a3h.u[p] = pk16(f[2 * p], f[2 * p + 1]);
    }

    const v4f vzero = {0.f, 0.f, 0.f, 0.f};
    FragU ones;
    ones.u[0] = ones.u[1] = ones.u[2] = ones.u[3] = 0x3C003C00u;

    // ---- vb2h = TSCALE*(b2 + rowsum(W2)) for own rows ----
    v4f vb2h[2];
#pragma unroll
    for (int jmt = 0; jmt < 2; ++jmt) {
        v4f t = __builtin_amdgcn_mfma_f32_16x16x32_f16(a2h[jmt][0].h, ones.h, vzero, 0, 0, 0);
        t = __builtin_amdgcn_mfma_f32_16x16x32_f16(a2h[jmt][1].h, ones.h, t, 0, 0, 0);
        const int j0 = 16 * (mtb + jmt) + 4 * q;
#pragma unroll
        for (int r = 0; r < 4; ++r) vb2h[jmt][r] = TSCALE * b2[j0 + r] - 0.5f * t[r];
    }
    // ---- vb3 partial: own half-rowsum of W3; b3 carried by half==0 only ----
    v4f vb3p;
    {
        v4f t = __builtin_amdgcn_mfma_f32_16x16x32_f16(a3h.h, ones.h, vzero, 0, 0, 0);
#pragma unroll
        for (int r = 0; r < 4; ++r)
            vb3p[r] = (half == 0 ? b3[(4 * q + r) & 7] : 0.0f) - 0.5f * t[r];
    }

    // ---- x state (duplicated across the pair; updates bit-identical) ----
    float xr[4];
    {
        float4 v = *(const float4*)(x0 + (size_t)(row0 + c) * 8 + 4 * (q & 1));
        xr[0] = v.x; xr[1] = v.y; xr[2] = v.z; xr[3] = v.w;
    }
    v2f gv = {0.f, 0.f};

    // ================= iteration 0: pure forward at (x0, t=0) =================
    {
        FragU bx;
        bx.u[0] = pk16(xr[0], xr[1]);
        bx.u[1] = pk16(xr[2], xr[3]);
        bx.u[2] = pk16(0.0f, 1.0f);
        bx.u[3] = 0u;
        v4f d1h[2];
#pragma unroll
        for (int jmt = 0; jmt < 2; ++jmt)
            d1h[jmt] = __builtin_amdgcn_mfma_f32_16x16x32_f16(a1h[jmt].h, bx.h, vzero, 0, 0, 0);
        unsigned ob[4];
        ob[0] = pk16(frcp3(d1h[0][0]), frcp3(d1h[0][1]));
        ob[1] = pk16(frcp3(d1h[0][2]), frcp3(d1h[0][3]));
        ob[2] = pk16(frcp3(d1h[1][0]), frcp3(d1h[1][1]));
        ob[3] = pk16(frcp3(d1h[1][2]), frcp3(d1h[1][3]));
#pragma unroll
        for (int k = 0; k < 4; ++k) ex1[w][lane][k] = ob[k];
        __syncthreads();
        unsigned sb[4];
#pragma unroll
        for (int k = 0; k < 4; ++k) sb[k] = ex1[ws][lane][k];
        FragU bs[2];
        if (half == 0) {
            bs[0].u[0] = ob[0]; bs[0].u[1] = ob[1]; bs[0].u[2] = sb[0]; bs[0].u[3] = sb[1];
            bs[1].u[0] = ob[2]; bs[1].u[1] = ob[3]; bs[1].u[2] = sb[2]; bs[1].u[3] = sb[3];
        } else {
            bs[0].u[0] = sb[0]; bs[0].u[1] = sb[1]; bs[0].u[2] = ob[0]; bs[0].u[3] = ob[1];
            bs[1].u[0] = sb[2]; bs[1].u[1] = sb[3]; bs[1].u[2] = ob[2]; bs[1].u[3] = ob[3];
        }
        v4f z2h[2];
#pragma unroll
        for (int jmt = 0; jmt < 2; ++jmt) {
            z2h[jmt] = __builtin_amdgcn_mfma_f32_16x16x32_f16(a2h[jmt][0].h, bs[0].h, vb2h[jmt], 0, 0, 0);
            z2h[jmt] = __builtin_amdgcn_mfma_f32_16x16x32_f16(a2h[jmt][1].h, bs[1].h, z2h[jmt], 0, 0, 0);
        }
        FragU buo;
        buo.u[0] = pk16(frcp3(z2h[0][0]), frcp3(z2h[0][1]));
        buo.u[1] = pk16(frcp3(z2h[0][2]), frcp3(z2h[0][3]));
        buo.u[2] = pk16(frcp3(z2h[1][0]), frcp3(z2h[1][1]));
        buo.u[3] = pk16(frcp3(z2h[1][2]), frcp3(z2h[1][3]));
        v4f d3p = __builtin_amdgcn_mfma_f32_16x16x32_f16(a3h.h, buo.h, vb3p, 0, 0, 0);
#pragma unroll
        for (int r = 0; r < 4; ++r) ex2[w][lane][r] = d3p[r];
        __syncthreads();
#pragma unroll
        for (int r = 0; r < 4; ++r) xr[r] = fmaf(dt, d3p[r] + ex2[ws][lane][r], xr[r]);
    }

    // ====== iterations i = 1..n-1: bwd(i-1) + fwd(i) from one L1 eval ======
    float tp = 0.0f; // t_{i-1}
    for (int i = 1; i < n; ++i) {
        FragU bx; // [x_i; t_{i-1}; 1]
        bx.u[0] = pk16(xr[0], xr[1]);
        bx.u[1] = pk16(xr[2], xr[3]);
        bx.u[2] = pk16(tp, 1.0f);
        bx.u[3] = 0u;
        tp += dt;
        v4f d1h[2];
#pragma unroll
        for (int jmt = 0; jmt < 2; ++jmt)
            d1h[jmt] = __builtin_amdgcn_mfma_f32_16x16x32_f16(a1h[jmt].h, bx.h, vzero, 0, 0, 0);

        // layer-1 own half: s1 (3-op chains), packed
        unsigned ob[4];
        ob[0] = pk16(frcp3(d1h[0][0]), frcp3(d1h[0][1]));
        ob[1] = pk16(frcp3(d1h[0][2]), frcp3(d1h[0][3]));
        ob[2] = pk16(frcp3(d1h[1][0]), frcp3(d1h[1][1]));
        ob[3] = pk16(frcp3(d1h[1][2]), frcp3(d1h[1][3]));

        // exchange: s-half only (sigma recomputed locally from same bits)
#pragma unroll
        for (int k = 0; k < 4; ++k) ex1[w][lane][k] = ob[k];
        __syncthreads();
        unsigned sb[4];
#pragma unroll
        for (int k = 0; k < 4; ++k) sb[k] = ex1[ws][lane][k];
        FragU bs[2], bo[2], bo2[2];
        if (half == 0) {
            bs[0].u[0] = ob[0]; bs[0].u[1] = ob[1]; bs[0].u[2] = sb[0]; bs[0].u[3] = sb[1];
            bs[1].u[0] = ob[2]; bs[1].u[1] = ob[3]; bs[1].u[2] = sb[2]; bs[1].u[3] = sb[3];
        } else {
            bs[0].u[0] = sb[0]; bs[0].u[1] = sb[1]; bs[0].u[2] = ob[0]; bs[0].u[3] = ob[1];
            bs[1].u[0] = sb[2]; bs[1].u[1] = sb[3]; bs[1].u[2] = ob[2]; bs[1].u[3] = ob[3];
        }
        // sigma1 from assembled s (bit-identical across the pair)
#pragma unroll
        for (int ks = 0; ks < 2; ++ks)
#pragma unroll
            for (int p = 0; p < 4; ++p) bo[ks].u[p] = pksig(bs[ks].u[p]);
        // dz2's B: sigma (x) c (C-layout constants; slots {mt0,mt2}/{mt1,mt3})
        bo2[0].u[0] = pmul16(bo[0].u[0], cpkC[0].x);
        bo2[0].u[1] = pmul16(bo[0].u[1], cpkC[0].y);
        bo2[0].u[2] = pmul16(bo[0].u[2], cpkC[2].x);
        bo2[0].u[3] = pmul16(bo[0].u[3], cpkC[2].y);
        bo2[1].u[0] = pmul16(bo[1].u[0], cpkC[1].x);
        bo2[1].u[1] = pmul16(bo[1].u[1], cpkC[1].y);
        bo2[1].u[2] = pmul16(bo[1].u[2], cpkC[3].x);
        bo2[1].u[3] = pmul16(bo[1].u[3], cpkC[3].y);

        v4f z2bh[2], sgh[2], dz2h[2];
#pragma unroll
        for (int jmt = 0; jmt < 2; ++jmt) {
            z2bh[jmt] = __builtin_amdgcn_mfma_f32_16x16x32_f16(a2h[jmt][0].h, bs[0].h, vb2h[jmt], 0, 0, 0);
            z2bh[jmt] = __builtin_amdgcn_mfma_f32_16x16x32_f16(a2h[jmt][1].h, bs[1].h, z2bh[jmt], 0, 0, 0);
            sgh[jmt] = __builtin_amdgcn_mfma_f32_16x16x32_f16(a2gh[jmt][0].h, bo[0].h, vzero, 0, 0, 0);
            sgh[jmt] = __builtin_amdgcn_mfma_f32_16x16x32_f16(a2gh[jmt][1].h, bo[1].h, sgh[jmt], 0, 0, 0);
            dz2h[jmt] = __builtin_amdgcn_mfma_f32_16x16x32_f16(a2h[jmt][0].h, bo2[0].h, vzero, 0, 0, 0);
            dz2h[jmt] = __builtin_amdgcn_mfma_f32_16x16x32_f16(a2h[jmt][1].h, bo2[1].h, dz2h[jmt], 0, 0, 0);
        }

        // layer-2 own half: s2, sigma2; gv += sigma2*sg; u = s2 - sigma2*dz2
        uint2 pu[2];
#pragma unroll
        for (int jmt = 0; jmt < 2; ++jmt) {
            v2f s01 = {frcp3(z2bh[jmt][0]), frcp3(z2bh[jmt][1])};
            v2f s23 = {frcp3(z2bh[jmt][2]), frcp3(z2bh[jmt][3])};
            v2f g01 = s01 - s01 * s01;
            v2f g23 = s23 - s23 * s23;
            gv += g01 * v2f{sgh[jmt][0], sgh[jmt][1]};
            gv += g23 * v2f{sgh[jmt][2], sgh[jmt][3]};
            v2f u01 = s01 - g01 * v2f{dz2h[jmt][0], dz2h[jmt][1]};
            v2f u23 = s23 - g23 * v2f{dz2h[jmt][2], dz2h[jmt][3]};
            pu[jmt].x = pk16v(u01);
            pu[jmt].y = pk16v(u23);
        }
        // d3 partial over own h-half; exchange partials (commutative add)
        FragU buo;
        buo.u[0] = pu[0].x; buo.u[1] = pu[0].y; buo.u[2] = pu[1].x; buo.u[3] = pu[1].y;
        v4f d3p = __builtin_amdgcn_mfma_f32_16x16x32_f16(a3h.h, buo.h, vb3p, 0, 0, 0);
#pragma unroll
        for (int r = 0; r < 4; ++r) ex2[w][lane][r] = d3p[r];
        __syncthreads();
#pragma unroll
        for (int r = 0; r < 4; ++r) xr[r] = fmaf(dt, d3p[r] + ex2[ws][lane][r], xr[r]);
    }

    // ============ final bwd at (x_n, t_{n-1}) ============
    {
        FragU bx;
        bx.u[0] = pk16(xr[0], xr[1]);
        bx.u[1] = pk16(xr[2], xr[3]);
        bx.u[2] = pk16(tp, 1.0f); // tp == (n-1)*dt
        bx.u[3] = 0u;
        v4f d1h[2];
#pragma unroll
        for (int jmt = 0; jmt < 2; ++jmt)
            d1h[jmt] = __builtin_amdgcn_mfma_f32_16x16x32_f16(a1h[jmt].h, bx.h, vzero, 0, 0, 0);
        unsigned ob[4];
        ob[0] = pk16(frcp3(d1h[0][0]), frcp3(d1h[0][1]));
        ob[1] = pk16(frcp3(d1h[0][2]), frcp3(d1h[0][3]));
        ob[2] = pk16(frcp3(d1h[1][0]), frcp3(d1h[1][1]));
        ob[3] = pk16(frcp3(d1h[1][2]), frcp3(d1h[1][3]));
#pragma unroll
        for (int k = 0; k < 4; ++k) ex1[w][lane][k] = ob[k];
        __syncthreads();
        unsigned sb[4];
#pragma unroll
        for (int k = 0; k < 4; ++k) sb[k] = ex1[ws][lane][k];
        FragU bs[2], bo[2];
        if (half == 0) {
            bs[0].u[0] = ob[0]; bs[0].u[1] = ob[1]; bs[0].u[2] = sb[0]; bs[0].u[3] = sb[1];
            bs[1].u[0] = ob[2]; bs[1].u[1] = ob[3]; bs[1].u[2] = sb[2]; bs[1].u[3] = sb[3];
        } else {
            bs[0].u[0] = sb[0]; bs[0].u[1] = sb[1]; bs[0].u[2] = ob[0]; bs[0].u[3] = ob[1];
            bs[1].u[0] = sb[2]; bs[1].u[1] = sb[3]; bs[1].u[2] = ob[2]; bs[1].u[3] = ob[3];
        }
#pragma unroll
        for (int ks = 0; ks < 2; ++ks)
#pragma unroll
            for (int p = 0; p < 4; ++p) bo[ks].u[p] = pksig(bs[ks].u[p]);
        v4f z2bh[2], sgh[2];
#pragma unroll
        for (int jmt = 0; jmt < 2; ++jmt) {
            z2bh[jmt] = __builtin_amdgcn_mfma_f32_16x16x32_f16(a2h[jmt][0].h, bs[0].h, vb2h[jmt], 0, 0, 0);
            z2bh[jmt] = __builtin_amdgcn_mfma_f32_16x16x32_f16(a2h[jmt][1].h, bs[1].h, z2bh[jmt], 0, 0, 0);
            sgh[jmt] = __builtin_amdgcn_mfma_f32_16x16x32_f16(a2gh[jmt][0].h, bo[0].h, vzero, 0, 0, 0);
            sgh[jmt] = __builtin_amdgcn_mfma_f32_16x16x32_f16(a2gh[jmt][1].h, bo[1].h, sgh[jmt], 0, 0, 0);
        }
#pragma unroll
        for (int jmt = 0; jmt < 2; ++jmt) {
            v2f s01 = {frcp3(z2bh[jmt][0]), frcp3(z2bh[jmt][1])};
            v2f s23 = {frcp3(z2bh[jmt][2]), frcp3(z2bh[jmt][3])};
            v2f g01 = s01 - s01 * s01;
            v2f g23 = s23 - s23 * s23;
            gv += g01 * v2f{sgh[jmt][0], sgh[jmt][1]};
            gv += g23 * v2f{sgh[jmt][2], sgh[jmt][3]};
        }
    }

    // ---- epilogue: per-wave q-reduce, then pair-sum via LDS ----
    float g = gv.x + gv.y;
    g += __shfl_xor(g, 16);
    g += __shfl_xor(g, 32);
    ex2[w][lane][0] = g;
    __syncthreads();
    g += ex2[ws][lane][0];
    if (half == 0 && q < 2) {
        float4 st = {xr[0], xr[1], xr[2], xr[3]};
        *(float4*)(out + (size_t)(row0 + c) * 8 + 4 * q) = st;
    }
    if (half == 0 && q == 0) out[(size_t)rows * 8 + row0 + c] = dt * g;
}

extern "C" void kernel_launch(void* const* d_in, const int* in_sizes, int n_in,
                              void* d_out, int out_size, void* d_ws, size_t ws_size,
                              hipStream_t stream) {
    const float* x0 = (const float*)d_in[0];
    const float* W1 = (const float*)d_in[1];
    const float* b1 = (const float*)d_in[2];
    const float* W2 = (const float*)d_in[3];
    const float* b2 = (const float*)d_in[4];
    const float* W3 = (const float*)d_in[5];
    const float* b3 = (const float*)d_in[6];
    const int* ns = (const int*)d_in[7];
    float* out = (float*)d_out;
    const int rows = in_sizes[0] / 8; // 32768

    // 16 rows per wave-PAIR, 2 pairs per 256-thread block -> rows/32 blocks.
    hipLaunchKernelGGL(cnf_fused, dim3(rows / 32), dim3(256), 0, stream,
                       x0, W1, b1, W2, b2, W3, b3, ns, out, rows);
}

// Round 9
// 185.760 us; speedup vs baseline: 1.3978x; 1.3150x over previous
//
#include <hip/hip_runtime.h>

// ContinuousNormalizingFlow: B=32768 rows, D=8, H=64, 100 Euler steps.
// R25: RESTORE R22 (measured best: 142.4us device, vs R16 baseline 161.4).
// The h-split TLP path (R23/R24) is closed: its ~150-reg live state spills
// under any waves>=3 launch bound (R23: 200MB, R24: 135MB scratch traffic),
// and spill-free operation requires the 2-wave budget where the split has
// no benefit. Session model, evidence-backed: the kernel is ISSUE-bound
// (R18: 2x issued work = 1.93x wall; R22: op-conserving reorder = 0%;
// R20/R21: op cuts = linear gains) with combined VALUBusy+MfmaUtil = 97.6%
// -- the SIMD issue capacity is saturated at this op count, and the op
// count is at its algebraic floor (sigmoid chains irreducible, affine
// work already folded into MFMA constants, MFMA count = minimal tiling).
// R22 = R21 s-form tanh + folded scales + deferred-bwd pipeline.

#define TSCALE 2.885390081777926815f // 2*log2(e)

// s = 1/(2^z + 1)  (z pre-scaled by 2*log2e). th = 1-2s. inf-safe.
__device__ __forceinline__ float frcp3(float z) {
    float e = __builtin_amdgcn_exp2f(z);
    return __builtin_amdgcn_rcpf(e + 1.0f);
}

typedef __attribute__((ext_vector_type(8))) _Float16 v8h; // 8 f16 (4 VGPRs)
typedef __attribute__((ext_vector_type(2))) __fp16 v2fp; // cvt_pkrtz result
typedef __attribute__((ext_vector_type(4))) float v4f;   // MFMA C/D
typedef __attribute__((ext_vector_type(2))) float v2f;   // packed fp32 pair

union FragU {
    v8h h;
    unsigned u[4];
};

// f16 pair pack: single v_cvt_pkrtz_f16_f32. a -> low half.
__device__ __forceinline__ unsigned pk16(float a, float b) {
    v2fp t = __builtin_amdgcn_cvt_pkrtz(a, b);
    return __builtin_bit_cast(unsigned, t);
}
__device__ __forceinline__ unsigned pk16v(v2f v) { return pk16(v.x, v.y); }

// sigma = s - s^2 = om/4 on a packed f16 pair (one v_pk_fma_f16).
__device__ __forceinline__ unsigned pksig(unsigned sp) {
    v2fp s = __builtin_bit_cast(v2fp, sp);
    v2fp r = s - s * s;
    return __builtin_bit_cast(unsigned, r);
}

// K-permutation for W2/W3 frags: slot (ks,q,jj) <- physical j.
__device__ __forceinline__ int physj(int ks, int q, int jj) {
    return 16 * (ks + 2 * (jj >> 2)) + 4 * q + (jj & 3);
}

// Rename C-fragment packs (ph[4]: per-mt {r01,r23}) into the B-frag pair.
__device__ __forceinline__ void rename(const uint2 ph[4], FragU bh[2]) {
#pragma unroll
    for (int ks = 0; ks < 2; ++ks) {
        bh[ks].u[0] = ph[ks].x;
        bh[ks].u[1] = ph[ks].y;
        bh[ks].u[2] = ph[ks + 2].x;
        bh[ks].u[3] = ph[ks + 2].y;
    }
}

__global__ __launch_bounds__(256, 2) void cnf_fused(
    const float* __restrict__ x0, const float* __restrict__ W1,
    const float* __restrict__ b1, const float* __restrict__ W2,
    const float* __restrict__ b2, const float* __restrict__ W3,
    const float* __restrict__ b3, const int* __restrict__ nsp,
    float* __restrict__ out, int rows) {
    const int tid = threadIdx.x;
    const int w = tid >> 6;
    const int lane = tid & 63;
    const int c = lane & 15;
    const int q = lane >> 4;
    const int row0 = blockIdx.x * 64 + w * 16;

    const int n = *nsp;
    const float dt = 1.0f / (float)n;

    // ---- A1 (x TSCALE): [x;t;1] layout. q0 jj0-3 = W1[:,0:4], q0 jj4 =
    // W1[:,8] (t), q0 jj5 = b1, q1 jj0-3 = W1[:,4:8], all else 0. ----
    FragU a1[4];
#pragma unroll
    for (int mt = 0; mt < 4; ++mt) {
        const int m = 16 * mt + c;
        float f[8] = {0.f, 0.f, 0.f, 0.f, 0.f, 0.f, 0.f, 0.f};
        if (q == 0) {
#pragma unroll
            for (int jj = 0; jj < 4; ++jj) f[jj] = TSCALE * W1[m * 9 + jj];
            f[4] = TSCALE * W1[m * 9 + 8];
            f[5] = TSCALE * b1[m];
        } else if (q == 1) {
#pragma unroll
            for (int jj = 0; jj < 4; ++jj) f[jj] = TSCALE * W1[m * 9 + 4 + jj];
        }
#pragma unroll
        for (int p = 0; p < 4; ++p) a1[mt].u[p] = pk16(f[2 * p], f[2 * p + 1]);
    }
    // ---- A2 (x -2*TSCALE, s-form) K-perm; a2g = 16*w3c*W2*w1r (B-op =
    // sigma1 = om1/4); a2d = 8*W2*(dt*w1t) (B-op = sigma1, output 2*dz2).
    FragU a2[4][2], a2g[4][2], a2d[4][2];
#pragma unroll
    for (int mt = 0; mt < 4; ++mt) {
        const int m = 16 * mt + c;
        float w3cm = 0.f;
#pragma unroll
        for (int d = 0; d < 8; ++d) w3cm += W3[d * 64 + m];
#pragma unroll
        for (int ks = 0; ks < 2; ++ks) {
            float f[8], fg[8], fd[8];
#pragma unroll
            for (int jj = 0; jj < 8; ++jj) {
                const int pj = physj(ks, q, jj);
                const float wv = W2[m * 64 + pj];
                float w1r = 0.f;
#pragma unroll
                for (int k = 0; k < 8; ++k) w1r += W1[pj * 9 + k];
                f[jj] = -2.0f * TSCALE * wv;
                fg[jj] = 16.0f * w3cm * wv * w1r;
                fd[jj] = 8.0f * wv * (dt * W1[pj * 9 + 8]);
            }
#pragma unroll
            for (int p = 0; p < 4; ++p) {
                a2[mt][ks].u[p] = pk16(f[2 * p], f[2 * p + 1]);
                a2g[mt][ks].u[p] = pk16(fg[2 * p], fg[2 * p + 1]);
                a2d[mt][ks].u[p] = pk16(fd[2 * p], fd[2 * p + 1]);
            }
        }
    }
    // ---- A3 (x -2, s-form): W3 rows duplicated (m -> m&7), K-permuted ----
    FragU a3[2];
#pragma unroll
    for (int ks = 0; ks < 2; ++ks) {
        float f[8];
#pragma unroll
        for (int jj = 0; jj < 8; ++jj)
            f[jj] = -2.0f * W3[(c & 7) * 64 + physj(ks, q, jj)];
#pragma unroll
        for (int p = 0; p < 4; ++p) a3[ks].u[p] = pk16(f[2 * p], f[2 * p + 1]);
    }

    const v4f vzero = {0.f, 0.f, 0.f, 0.f};
    // ---- all-ones B-frag for setup rowsum MFMAs ----
    FragU ones;
    ones.u[0] = ones.u[1] = ones.u[2] = ones.u[3] = 0x3C003C00u;

    // ---- vb2 = TSCALE*(b2 + rowsum(W2)) via a2*ones (a2 = -2*TS*W2) ----
    v4f vb2[4];
#pragma unroll
    for (int mt = 0; mt < 4; ++mt) {
        v4f t = __builtin_amdgcn_mfma_f32_16x16x32_f16(a2[mt][0].h, ones.h, vzero, 0, 0, 0);
        t = __builtin_amdgcn_mfma_f32_16x16x32_f16(a2[mt][1].h, ones.h, t, 0, 0, 0);
        const int j0 = 16 * mt + 4 * q;
#pragma unroll
        for (int r = 0; r < 4; ++r)
            vb2[mt][r] = TSCALE * b2[j0 + r] - 0.5f * t[r];
    }
    // ---- vb3 = b3 + rowsum(W3) via a3*ones (a3 = -2*W3) ----
    v4f vb3;
    {
        v4f t = __builtin_amdgcn_mfma_f32_16x16x32_f16(a3[0].h, ones.h, vzero, 0, 0, 0);
        t = __builtin_amdgcn_mfma_f32_16x16x32_f16(a3[1].h, ones.h, t, 0, 0, 0);
#pragma unroll
        for (int r = 0; r < 4; ++r) vb3[r] = b3[(4 * q + r) & 7] - 0.5f * t[r];
    }

    // ---- x state: ALL lanes hold xr[r] = x[row0+c][(4q+r)&7] (duplicated) ----
    float xr[4];
    {
        float4 v = *(const float4*)(x0 + (size_t)(row0 + c) * 8 + 4 * (q & 1));
        xr[0] = v.x; xr[1] = v.y; xr[2] = v.z; xr[3] = v.w;
    }
    v2f gv = {0.f, 0.f};

    // ================= iteration 0: pure forward at (x0, t=0) =================
    {
        FragU bx;
        bx.u[0] = pk16(xr[0], xr[1]);
        bx.u[1] = pk16(xr[2], xr[3]);
        bx.u[2] = pk16(0.0f, 1.0f);
        bx.u[3] = 0u;
        v4f d1[4];
#pragma unroll
        for (int mt = 0; mt < 4; ++mt)
            d1[mt] = __builtin_amdgcn_mfma_f32_16x16x32_f16(a1[mt].h, bx.h, vzero, 0, 0, 0);
        uint2 ps[4];
#pragma unroll
        for (int mt = 0; mt < 4; ++mt) {
            ps[mt].x = pk16(frcp3(d1[mt][0]), frcp3(d1[mt][1]));
            ps[mt].y = pk16(frcp3(d1[mt][2]), frcp3(d1[mt][3]));
        }
        FragU bs[2];
        rename(ps, bs);
        v4f d2[4];
#pragma unroll
        for (int mt = 0; mt < 4; ++mt) {
            d2[mt] = __builtin_amdgcn_mfma_f32_16x16x32_f16(a2[mt][0].h, bs[0].h, vb2[mt], 0, 0, 0);
            d2[mt] = __builtin_amdgcn_mfma_f32_16x16x32_f16(a2[mt][1].h, bs[1].h, d2[mt], 0, 0, 0);
        }
#pragma unroll
        for (int mt = 0; mt < 4; ++mt) {
            ps[mt].x = pk16(frcp3(d2[mt][0]), frcp3(d2[mt][1]));
            ps[mt].y = pk16(frcp3(d2[mt][2]), frcp3(d2[mt][3]));
        }
        FragU bs2[2];
        rename(ps, bs2);
        v4f d3;
        d3 = __builtin_amdgcn_mfma_f32_16x16x32_f16(a3[0].h, bs2[0].h, vb3, 0, 0, 0);
        d3 = __builtin_amdgcn_mfma_f32_16x16x32_f16(a3[1].h, bs2[1].h, d3, 0, 0, 0);
#pragma unroll
        for (int r = 0; r < 4; ++r) xr[r] = fmaf(dt, d3[r], xr[r]);
    }

    // ---- deferred-bwd pipeline state: sigma1 frags + sigma2 (f32) of the
    // previous loop iteration. Zero-init => first pass does A2g*0 (no-op). ----
    FragU boP[2];
    boP[0].u[0] = boP[0].u[1] = boP[0].u[2] = boP[0].u[3] = 0u;
    boP[1].u[0] = boP[1].u[1] = boP[1].u[2] = boP[1].u[3] = 0u;
    v2f gp01[4], gp23[4];
#pragma unroll
    for (int mt = 0; mt < 4; ++mt) {
        gp01[mt] = v2f{0.f, 0.f};
        gp23[mt] = v2f{0.f, 0.f};
    }

    // ====== iterations i = 1..n-1: bwd(i-1) + fwd(i) from one L1 eval;
    // the sg/gv (logdet) part of bwd(i-1) is deferred into iteration i ======
    float tp = 0.0f; // t_{i-1}
    for (int i = 1; i < n; ++i) {
        FragU bx; // [x_i; t_{i-1}; 1]
        bx.u[0] = pk16(xr[0], xr[1]);
        bx.u[1] = pk16(xr[2], xr[3]);
        bx.u[2] = pk16(tp, 1.0f);
        bx.u[3] = 0u;
        tp += dt;
        v4f d1[4];
#pragma unroll
        for (int mt = 0; mt < 4; ++mt)
            d1[mt] = __builtin_amdgcn_mfma_f32_16x16x32_f16(a1[mt].h, bx.h, vzero, 0, 0, 0);

        // ---- deferred sg/gv of PREVIOUS iteration: fills d1's latency ----
#pragma unroll
        for (int mt = 0; mt < 4; ++mt) {
            v4f sgp = __builtin_amdgcn_mfma_f32_16x16x32_f16(a2g[mt][0].h, boP[0].h, vzero, 0, 0, 0);
            sgp = __builtin_amdgcn_mfma_f32_16x16x32_f16(a2g[mt][1].h, boP[1].h, sgp, 0, 0, 0);
            gv += gp01[mt] * v2f{sgp[0], sgp[1]};
            gv += gp23[mt] * v2f{sgp[2], sgp[3]};
        }

        // layer 1: s1 packed (3-op chains); sigma1 = s1 - s1^2 packed f16
        uint2 psb[4], psg[4];
#pragma unroll
        for (int mt = 0; mt < 4; ++mt) {
            psb[mt].x = pk16(frcp3(d1[mt][0]), frcp3(d1[mt][1]));
            psb[mt].y = pk16(frcp3(d1[mt][2]), frcp3(d1[mt][3]));
            psg[mt].x = pksig(psb[mt].x);
            psg[mt].y = pksig(psb[mt].y);
        }
        FragU bs[2];
        rename(psb, bs);
        rename(psg, boP); // overwrite pipeline state (deferred block read it)

        v4f z2b[4], dz2[4];
#pragma unroll
        for (int mt = 0; mt < 4; ++mt) {
            z2b[mt] = __builtin_amdgcn_mfma_f32_16x16x32_f16(a2[mt][0].h, bs[0].h, vb2[mt], 0, 0, 0);
            z2b[mt] = __builtin_amdgcn_mfma_f32_16x16x32_f16(a2[mt][1].h, bs[1].h, z2b[mt], 0, 0, 0);
            dz2[mt] = __builtin_amdgcn_mfma_f32_16x16x32_f16(a2d[mt][0].h, boP[0].h, vzero, 0, 0, 0);
            dz2[mt] = __builtin_amdgcn_mfma_f32_16x16x32_f16(a2d[mt][1].h, boP[1].h, dz2[mt], 0, 0, 0);
        }

        // layer 2: s2 (3-op); sigma2 = s2-s2^2 (saved for deferred gv);
        // u = s2 - sigma2*dz2  (d3 B-operand; tf = 1-2u exactly)
        uint2 pu[4];
#pragma unroll
        for (int mt = 0; mt < 4; ++mt) {
            v2f s01 = {frcp3(z2b[mt][0]), frcp3(z2b[mt][1])};
            v2f s23 = {frcp3(z2b[mt][2]), frcp3(z2b[mt][3])};
            v2f g01 = s01 - s01 * s01;
            v2f g23 = s23 - s23 * s23;
            gp01[mt] = g01;
            gp23[mt] = g23;
            v2f u01 = s01 - g01 * v2f{dz2[mt][0], dz2[mt][1]};
            v2f u23 = s23 - g23 * v2f{dz2[mt][2], dz2[mt][3]};
            pu[mt].x = pk16v(u01);
            pu[mt].y = pk16v(u23);
        }
        FragU bu[2];
        rename(pu, bu);
        v4f d3;
        d3 = __builtin_amdgcn_mfma_f32_16x16x32_f16(a3[0].h, bu[0].h, vb3, 0, 0, 0);
        d3 = __builtin_amdgcn_mfma_f32_16x16x32_f16(a3[1].h, bu[1].h, d3, 0, 0, 0);
#pragma unroll
        for (int r = 0; r < 4; ++r) xr[r] = fmaf(dt, d3[r], xr[r]);
    }

    // ---- flush deferred sg/gv of the last loop iteration ----
#pragma unroll
    for (int mt = 0; mt < 4; ++mt) {
        v4f sgp = __builtin_amdgcn_mfma_f32_16x16x32_f16(a2g[mt][0].h, boP[0].h, vzero, 0, 0, 0);
        sgp = __builtin_amdgcn_mfma_f32_16x16x32_f16(a2g[mt][1].h, boP[1].h, sgp, 0, 0, 0);
        gv += gp01[mt] * v2f{sgp[0], sgp[1]};
        gv += gp23[mt] * v2f{sgp[2], sgp[3]};
    }

    // ============ final bwd at (x_n, t_{n-1}) ============
    {
        FragU bx;
        bx.u[0] = pk16(xr[0], xr[1]);
        bx.u[1] = pk16(xr[2], xr[3]);
        bx.u[2] = pk16(tp, 1.0f); // tp == (n-1)*dt
        bx.u[3] = 0u;
        v4f d1[4];
#pragma unroll
        for (int mt = 0; mt < 4; ++mt)
            d1[mt] = __builtin_amdgcn_mfma_f32_16x16x32_f16(a1[mt].h, bx.h, vzero, 0, 0, 0);
        uint2 psb[4], psg[4];
#pragma unroll
        for (int mt = 0; mt < 4; ++mt) {
            psb[mt].x = pk16(frcp3(d1[mt][0]), frcp3(d1[mt][1]));
            psb[mt].y = pk16(frcp3(d1[mt][2]), frcp3(d1[mt][3]));
            psg[mt].x = pksig(psb[mt].x);
            psg[mt].y = pksig(psb[mt].y);
        }
        FragU bs[2], bo[2];
        rename(psb, bs);
        rename(psg, bo);
        v4f z2b[4], sg[4];
#pragma unroll
        for (int mt = 0; mt < 4; ++mt) {
            z2b[mt] = __builtin_amdgcn_mfma_f32_16x16x32_f16(a2[mt][0].h, bs[0].h, vb2[mt], 0, 0, 0);
            z2b[mt] = __builtin_amdgcn_mfma_f32_16x16x32_f16(a2[mt][1].h, bs[1].h, z2b[mt], 0, 0, 0);
            sg[mt] = __builtin_amdgcn_mfma_f32_16x16x32_f16(a2g[mt][0].h, bo[0].h, vzero, 0, 0, 0);
            sg[mt] = __builtin_amdgcn_mfma_f32_16x16x32_f16(a2g[mt][1].h, bo[1].h, sg[mt], 0, 0, 0);
        }
#pragma unroll
        for (int mt = 0; mt < 4; ++mt) {
            v2f s01 = {frcp3(z2b[mt][0]), frcp3(z2b[mt][1])};
            v2f s23 = {frcp3(z2b[mt][2]), frcp3(z2b[mt][3])};
            v2f g01 = s01 - s01 * s01;
            v2f g23 = s23 - s23 * s23;
            gv += g01 * v2f{sg[mt][0], sg[mt][1]};
            gv += g23 * v2f{sg[mt][2], sg[mt][3]};
        }
    }

    // ---- epilogue ----
    float g = gv.x + gv.y;
    g += __shfl_xor(g, 16);
    g += __shfl_xor(g, 32);
    if (q < 2) {
        float4 st = {xr[0], xr[1], xr[2], xr[3]};
        *(float4*)(out + (size_t)(row0 + c) * 8 + 4 * q) = st;
    }
    if (q == 0) out[(size_t)rows * 8 + row0 + c] = dt * g;
}

extern "C" void kernel_launch(void* const* d_in, const int* in_sizes, int n_in,
                              void* d_out, int out_size, void* d_ws, size_t ws_size,
                              hipStream_t stream) {
    const float* x0 = (const float*)d_in[0];
    const float* W1 = (const float*)d_in[1];
    const float* b1 = (const float*)d_in[2];
    const float* W2 = (const float*)d_in[3];
    const float* b2 = (const float*)d_in[4];
    const float* W3 = (const float*)d_in[5];
    const float* b3 = (const float*)d_in[6];
    const int* ns = (const int*)d_in[7];
    float* out = (float*)d_out;
    const int rows = in_sizes[0] / 8; // 32768

    hipLaunchKernelGGL(cnf_fused, dim3(rows / 64), dim3(256), 0, stream,
                       x0, W1, b1, W2, b2, W3, b3, ns, out, rows);
}